// Round 11
// baseline (190.384 us; speedup 1.0000x reference)
//
#include <hip/hip_runtime.h>
#include <math.h>

typedef __attribute__((ext_vector_type(8))) short bf16x8;
typedef __attribute__((ext_vector_type(4))) float f32x4;

#define NB 16
#define NS 720
#define NC 862
#define NP 24
#define NQ 30
#define NDM 128
#define NPRED 336
#define BC (NB*NC)          /* 13792 */
#define SCH 10
#define SLEN 72             /* 720/10 */
#define PBASE (4*BC)        /* stats partials (floats) */
#define WOFF_F (24*BC)      /* float offset of bf16 blobs */
#define NCOL (NB*NC)        /* fused N dimension = 13792 */
#define MT 24               /* m-tiles (384 = 336 padded) */

__device__ __forceinline__ short f2bf(float f) {
    union { float f; unsigned u; } v; v.f = f;
    unsigned r = v.u + 0x7FFFu + ((v.u >> 16) & 1u);   // round-to-nearest-even
    return (short)(r >> 16);
}

__device__ __forceinline__ unsigned cvt_pk_bf16(float a, float b) {
    unsigned r;
    asm("v_cvt_pk_bf16_f32 %0, %1, %2" : "=v"(r) : "v"(a), "v"(b));
    return r;
}

// gelu tanh-form (exp saturates safely at extremes); |err vs exact| <~2e-4
__device__ __forceinline__ float gelu_f(float h) {
    float z2 = h * h;
    float zz = h * (0.79788456f + 0.035677408f * z2);
    float e  = __expf(-2.f * zz);
    return h * __builtin_amdgcn_rcpf(1.f + e);
}

// ---------------- stats: two-phase, deterministic ----------------
__global__ __launch_bounds__(256) void stats_partial_k(const float* __restrict__ x,
                                                       float* __restrict__ ws) {
    int b = blockIdx.x, half = blockIdx.y, ch = blockIdx.z;
    int t = half * 256 + threadIdx.x;
    if (t >= NC / 2) return;
    const float2* xp = (const float2*)(x + ((size_t)b * NS + (size_t)ch * SLEN) * NC) + t;
    float2 s = {0.f, 0.f}, sq = {0.f, 0.f};
    #pragma unroll 4
    for (int i = 0; i < SLEN; ++i) {
        float2 v = xp[(size_t)i * (NC / 2)];
        s.x += v.x; s.y += v.y;
        sq.x += v.x * v.x; sq.y += v.y * v.y;
    }
    int idx = b * NC + t * 2;
    float* ps = ws + PBASE;
    *(float2*)&ps[(size_t)ch * BC + idx] = s;
    *(float2*)&ps[(size_t)(SCH + ch) * BC + idx] = sq;
}

__global__ __launch_bounds__(256) void stats_final_k(float* __restrict__ ws,
                                                     const float* __restrict__ revw,
                                                     const float* __restrict__ revb) {
    int idx = blockIdx.x * 256 + threadIdx.x;
    if (idx >= BC) return;
    const float* ps = ws + PBASE;
    float s = 0.f, sq = 0.f;
    #pragma unroll
    for (int ch = 0; ch < SCH; ++ch) {
        s  += ps[(size_t)ch * BC + idx];
        sq += ps[(size_t)(SCH + ch) * BC + idx];
    }
    int c = idx % NC;
    float mean  = s * (1.f / NS);
    float var   = sq * (1.f / NS) - mean * mean;
    float stdev = sqrtf(var + 1e-5f);
    float rstd  = 1.f / stdev;
    float aw = revw[c] * rstd;
    float u  = stdev / (revw[c] + 1e-10f);
    ws[idx]          = aw;                     // AW
    ws[BC + idx]     = revb[c] - mean * aw;    // BW
    ws[2 * BC + idx] = u;                      // U
    ws[3 * BC + idx] = mean - revb[c] * u;     // V
}

// ---------------- W1 frag blob (A of H-GEMM), frag-major ----------------
__global__ __launch_bounds__(256) void w1prep_k(const float* __restrict__ W1,
                                                unsigned short* __restrict__ W1FF) {
    int p = blockIdx.x, tid = threadIdx.x;
    const float* w1 = W1 + (size_t)(NP + p) * NDM * NQ;   // layer 1 only
    #pragma unroll
    for (int pass = 0; pass < 2; ++pass) {
        int s = pass * 256 + tid;                  // 512 frag-lanes
        int l = s & 63, lr = l & 15, lg = l >> 4;
        int dt = s >> 6;
        int d = dt * 16 + lr;
        bf16x8 v;
        #pragma unroll
        for (int j = 0; j < 8; ++j) {
            int q = 8 * lg + j;
            v[j] = f2bf(q < NQ ? w1[d * NQ + q] : 0.f);
        }
        ((bf16x8*)(W1FF + (size_t)p * 4096))[s] = v;
    }
}

// ---------------- G_p = PW_p(336x30) @ W2_p(30x128), bf16 frag-major ---------------
// GF frag (p, mt, ks): lane l=(lr,lg): rows m = mt*16+lr, k = d = ks*32+8*lg+j.
__global__ __launch_bounds__(256) void gprep_k(const float* __restrict__ pw,
                                               const float* __restrict__ W2,
                                               unsigned short* __restrict__ GF) {
    __shared__ float pws[16][NQ + 2];          // pw[m][q*24+p] for this (p, mt)
    int p = blockIdx.x, mt = blockIdx.y, tid = threadIdx.x;
    if (tid < 240) {
        #pragma unroll
        for (int k = 0; k < 2; ++k) {
            int idx = tid + k * 240;           // 480 = 16 m x 30 q
            int mi = idx / NQ, q = idx % NQ;
            int m = mt * 16 + mi;
            pws[mi][q] = (m < NPRED) ? pw[(size_t)m * NS + q * NP + p] : 0.f;
        }
    }
    __syncthreads();
    int ks = tid >> 6, l = tid & 63, lr = l & 15, lg = l >> 4;
    const float* w2 = W2 + (size_t)(NP + p) * NQ * NDM + ks * 32 + lg * 8;
    float g[8] = {0, 0, 0, 0, 0, 0, 0, 0};
    for (int q = 0; q < NQ; ++q) {
        float pv = pws[lr][q];
        #pragma unroll
        for (int j = 0; j < 8; ++j) g[j] += pv * w2[q * NDM + j];
    }
    bf16x8 v;
    #pragma unroll
    for (int j = 0; j < 8; ++j) v[j] = f2bf(g[j]);
    ((bf16x8*)GF)[((size_t)(p * MT + mt) * 4 + ks) * 64 + l] = v;
}

// ---------------- mega: out = Sigma_p G_p @ gelu(W1_p @ Xs_p), fused denorm ---------
// 512 thr / 8 waves, n-tile 64 (fused n = b*NC+c), grid 216. Per p:
//   stage Xs (norm+cvt_pk -> XsB) ; barrier ; H: wave w = d-tile w (4 MFMA) ;
//   gelu -> HB (swizzled) ; barrier ; out-acc: wave w = mt {w, w+8, w+16} x 4 nt
//   (48 MFMA, A-frags direct from L2 GF blob). Epilogue: +pb, denorm U/V, store.
__global__ __launch_bounds__(512, 2) void mega_k(const float* __restrict__ x,
        const unsigned short* __restrict__ W1FF, const unsigned short* __restrict__ GF,
        const float* __restrict__ pb, const float* __restrict__ ws,
        float* __restrict__ out) {
    __shared__ __align__(16) short XsB[4 * 64 * 8];     // 4KB : rows=n(64), K=q(32)
    __shared__ __align__(16) short HB [16 * 64 * 8];    // 16KB: rows=n(64), K=d(128)
    int tid = threadIdx.x;
    int n0 = blockIdx.x * 64;
    int w = tid >> 6, l = tid & 63, lr = l & 15, lg = l >> 4;
    f32x4 zf = {0.f, 0.f, 0.f, 0.f};
    f32x4 acc[3][4];
    #pragma unroll
    for (int t = 0; t < 3; ++t)
        #pragma unroll
        for (int nt = 0; nt < 4; ++nt) acc[t][nt] = zf;

    // staging role (threads 0..255): thread -> (n = tid&63, kb = tid>>6 in [0,4))
    int cS = tid & 63, kbS = (tid >> 6) & 3;
    int n_s = n0 + cS; if (n_s > NCOL - 1) n_s = NCOL - 1;
    float aw = ws[n_s];
    float bw = ws[BC + n_s];
    int b_s = n_s / NC, c_s = n_s - b_s * NC;
    const float* xb = x + (size_t)b_s * NS * NC + c_s;

    for (int p = 0; p < NP; ++p) {
        if (tid < 256) {   // stage Xs for this p
            float xs[8];
            #pragma unroll
            for (int j = 0; j < 8; ++j) {
                int q = kbS * 8 + j;
                xs[j] = (q < NQ) ? xb[(size_t)(q * NP + p) * NC] * aw + bw : 0.f;
            }
            unsigned u[4];
            #pragma unroll
            for (int i = 0; i < 4; ++i) u[i] = cvt_pk_bf16(xs[2 * i], xs[2 * i + 1]);
            *(uint4*)&XsB[(size_t)(kbS * 64 + (cS ^ kbS)) * 8] = *(uint4*)u;
        }
        __syncthreads();                      // XsB ready; HB free (prev out-acc done)

        // H = W1 @ Xs : M=128(d), N=64(n), K=32. Wave w owns d-tile w.
        const bf16x8* w1p = (const bf16x8*)(W1FF + (size_t)p * 4096);
        bf16x8 a0 = w1p[w * 64 + l];
        f32x4 hc[4];
        #pragma unroll
        for (int nt = 0; nt < 4; ++nt) {
            bf16x8 bfr = *(const bf16x8*)&XsB[(size_t)(lg * 64 + ((nt * 16 + lr) ^ lg)) * 8];
            hc[nt] = __builtin_amdgcn_mfma_f32_16x16x32_bf16(a0, bfr, zf, 0, 0, 0);
        }
        // gelu + write H^T into HB (rows=n, K=d), XOR swizzle
        {
            int d0 = w * 16 + 4 * lg;
            int kb = d0 >> 3, sub = d0 & 7;   // sub in {0,4}
            #pragma unroll
            for (int nt = 0; nt < 4; ++nt) {
                unsigned u0 = cvt_pk_bf16(gelu_f(hc[nt][0]), gelu_f(hc[nt][1]));
                unsigned u1 = cvt_pk_bf16(gelu_f(hc[nt][2]), gelu_f(hc[nt][3]));
                int col = nt * 16 + lr;
                unsigned* dst = (unsigned*)&HB[(size_t)(kb * 64 + (col ^ kb)) * 8 + sub];
                dst[0] = u0; dst[1] = u1;
            }
        }
        __syncthreads();                      // HB ready

        // out-acc: acc += G_p @ H_p. M-tiles {w, w+8, w+16}, N=64, K=128 (4 ks).
        const bf16x8* gp = (const bf16x8*)GF + (size_t)p * MT * 4 * 64 + l;
        #pragma unroll
        for (int ks = 0; ks < 4; ++ks) {
            bf16x8 bfr[4];
            #pragma unroll
            for (int nt = 0; nt < 4; ++nt) {
                int kb = ks * 4 + lg;
                bfr[nt] = *(const bf16x8*)&HB[(size_t)(kb * 64 + ((nt * 16 + lr) ^ kb)) * 8];
            }
            #pragma unroll
            for (int t = 0; t < 3; ++t) {
                int mt = w + 8 * t;
                bf16x8 a = gp[(size_t)(mt * 4 + ks) * 64];
                #pragma unroll
                for (int nt = 0; nt < 4; ++nt)
                    acc[t][nt] = __builtin_amdgcn_mfma_f32_16x16x32_bf16(a, bfr[nt],
                                                                        acc[t][nt], 0, 0, 0);
            }
        }
    }

    // epilogue: bias + denorm (U/V indexed by fused n), store
    #pragma unroll
    for (int t = 0; t < 3; ++t) {
        int mt = w + 8 * t;
        #pragma unroll
        for (int r = 0; r < 4; ++r) {
            int pr = mt * 16 + 4 * lg + r;
            if (pr >= NPRED) continue;
            float bias = pb[pr];
            #pragma unroll
            for (int nt = 0; nt < 4; ++nt) {
                int n = n0 + nt * 16 + lr;
                if (n >= NCOL) continue;
                int bb = n / NC;
                int cc = n - bb * NC;
                out[((size_t)bb * NPRED + pr) * NC + cc] =
                    (acc[t][nt][r] + bias) * ws[2 * BC + n] + ws[3 * BC + n];
            }
        }
    }
}

extern "C" void kernel_launch(void* const* d_in, const int* in_sizes, int n_in,
                              void* d_out, int out_size, void* d_ws, size_t ws_size,
                              hipStream_t stream) {
    const float* x   = (const float*)d_in[0];
    const float* W1  = (const float*)d_in[1];
    const float* W2  = (const float*)d_in[2];
    const float* pw  = (const float*)d_in[3];
    const float* pb  = (const float*)d_in[4];
    const float* rw  = (const float*)d_in[5];
    const float* rb  = (const float*)d_in[6];
    float* out = (float*)d_out;
    float* ws  = (float*)d_ws;
    unsigned short* W1FF = (unsigned short*)(ws + WOFF_F);         // 24*4096 shorts
    unsigned short* GF   = W1FF + NP * 4096;                       // 24*24*4*512 shorts

    stats_partial_k<<<dim3(NB, 2, SCH), 256, 0, stream>>>(x, ws);
    w1prep_k<<<dim3(NP), 256, 0, stream>>>(W1, W1FF);
    gprep_k<<<dim3(NP, MT), 256, 0, stream>>>(pw, W2, GF);
    stats_final_k<<<dim3((BC + 255) / 256), 256, 0, stream>>>(ws, rw, rb);
    mega_k<<<dim3((NCOL + 63) / 64), 512, 0, stream>>>(x, W1FF, GF, pb, ws, out);
}